// Round 10
// baseline (247.674 us; speedup 1.0000x reference)
//
#include <hip/hip_runtime.h>
#include <math.h>

#define Bn 32
#define Ln 512
#define Hn 256
#define NHn 4
#define DHn 64

typedef __attribute__((ext_vector_type(8))) short bf16x8;
typedef __attribute__((ext_vector_type(4))) float f32x4;
typedef unsigned int uint32;

__device__ __forceinline__ short f2b(float f) {
    union { float f; uint32 u; } v; v.f = f;
    uint32 r = (v.u + 0x7FFFu + ((v.u >> 16) & 1u)) >> 16;
    return (short)r;
}
__device__ __forceinline__ float b2f(short h) {
    union { uint32 u; float f; } v; v.u = ((uint32)(unsigned short)h) << 16;
    return v.f;
}
// fast tanh: (e^{2x}-1)/(e^{2x}+1) = 1 - 2/(e^{2x}+1); exact limits at +-inf
__device__ __forceinline__ float fast_tanh(float x) {
    float e = __expf(2.f * x);
    return 1.f - 2.f * __builtin_amdgcn_rcpf(e + 1.f);
}
__device__ __forceinline__ float fast_sigmoid(float x) {
    return __builtin_amdgcn_rcpf(1.f + __expf(-x));
}

// ---------------- weights fp32 -> bf16 (tiny: 320 blocks); pred init ----------------
__global__ __launch_bounds__(256) void conv_kernel(
    const float* __restrict__ Wq, const float* __restrict__ Wk,
    const float* __restrict__ Wv, const float* __restrict__ Wtq,
    const float* __restrict__ Wd, const float* __restrict__ bt,
    short* __restrict__ wb, float* __restrict__ pred)
{
    if (blockIdx.x == 0 && threadIdx.x < Bn) pred[threadIdx.x] = bt[0];
    size_t off = ((size_t)blockIdx.x * 256 + threadIdx.x) * 4;   // < 5*65536
    int w = (int)(off >> 16);
    size_t wi = off & 65535;
    const float* src = (w == 0) ? Wq : (w == 1) ? Wk : (w == 2) ? Wv : (w == 3) ? Wtq : Wd;
    float4 v = *(const float4*)(src + wi);
    short4 o; o.x = f2b(v.x); o.y = f2b(v.y); o.z = f2b(v.z); o.w = f2b(v.w);
    *(short4*)(wb + off) = o;
}

// ---------------- shared 64x64 bf16 MFMA NT-GEMM tile, K=Hn, with optional fp32
// operand conversion during LDS staging (bit-identical f2b rounding) ----------------
struct Acc { f32x4 t[4]; };

template<bool AF, bool BF>
__device__ __forceinline__ void gemm_tile_64_cv(
    const void* __restrict__ Ap,   // rows m0.., row stride Hn (fp32 if AF else bf16)
    const void* __restrict__ Bp,   // rows n0.., row stride Hn (fp32 if BF else bf16)
    short* As, short* Bs, Acc& acc)
{
    const int tid = threadIdx.x;
    const int lane = tid & 63, w = tid >> 6;
    const int quad = lane >> 4, lm = lane & 15;
    const int srow = tid >> 3;   // 0..31
    const int slot = tid & 7;

    for (int k0 = 0; k0 < Hn; k0 += 64) {
        __syncthreads();
#pragma unroll
        for (int iss = 0; iss < 2; ++iss) {
            int r = srow + iss * 32;
            bf16x8 av, bv;
            if (AF) {
                const float* A = (const float*)Ap;
                float4 u0 = *(const float4*)(A + (size_t)r * Hn + k0 + slot * 8);
                float4 u1 = *(const float4*)(A + (size_t)r * Hn + k0 + slot * 8 + 4);
                av[0] = f2b(u0.x); av[1] = f2b(u0.y); av[2] = f2b(u0.z); av[3] = f2b(u0.w);
                av[4] = f2b(u1.x); av[5] = f2b(u1.y); av[6] = f2b(u1.z); av[7] = f2b(u1.w);
            } else {
                av = *(const bf16x8*)((const short*)Ap + (size_t)r * Hn + k0 + slot * 8);
            }
            if (BF) {
                const float* B = (const float*)Bp;
                float4 u0 = *(const float4*)(B + (size_t)r * Hn + k0 + slot * 8);
                float4 u1 = *(const float4*)(B + (size_t)r * Hn + k0 + slot * 8 + 4);
                bv[0] = f2b(u0.x); bv[1] = f2b(u0.y); bv[2] = f2b(u0.z); bv[3] = f2b(u0.w);
                bv[4] = f2b(u1.x); bv[5] = f2b(u1.y); bv[6] = f2b(u1.z); bv[7] = f2b(u1.w);
            } else {
                bv = *(const bf16x8*)((const short*)Bp + (size_t)r * Hn + k0 + slot * 8);
            }
            *(bf16x8*)(As + r * 72 + slot * 8) = av;
            *(bf16x8*)(Bs + r * 72 + slot * 8) = bv;
        }
        __syncthreads();
#pragma unroll
        for (int ks = 0; ks < 2; ++ks) {
            bf16x8 a = *(const bf16x8*)(As + (w * 16 + lm) * 72 + ks * 32 + quad * 8);
#pragma unroll
            for (int kt = 0; kt < 4; ++kt) {
                bf16x8 b = *(const bf16x8*)(Bs + (kt * 16 + lm) * 72 + ks * 32 + quad * 8);
                acc.t[kt] = __builtin_amdgcn_mfma_f32_16x16x32_bf16(a, b, acc.t[kt], 0, 0, 0);
            }
        }
    }
}

// ---------------- fused QKV+TQ projection, staging A directly from x fp32 ----------------
// XCD-chunked swizzle: each XCD owns a contiguous m-range with all 16 (tensor,col)
// variants, so the shared A-tile is fetched from HBM once per XCD instead of 8x.
__global__ __launch_bounds__(256) void proj_kernel(
    const float* __restrict__ x, const short* __restrict__ wb,
    const float* __restrict__ bq, const float* __restrict__ bk,
    const float* __restrict__ bv, const float* __restrict__ btq,
    short* __restrict__ qb, short* __restrict__ kb,
    short* __restrict__ vt, short* __restrict__ tqb)
{
    __shared__ short As[64 * 72];
    __shared__ short Bs[64 * 72];
    const int bid = blockIdx.y * 16 + blockIdx.x;      // dispatch-linear id
    const int xcd = bid & 7, idx = bid >> 3;
    const int v = xcd * 512 + idx;                     // bijective: 4096 blocks
    const int tensor = (v & 15) >> 2;
    const int ncol0 = (v & 3) * 64;
    const int m0 = (v >> 4) * 64;
    const float* A = x + (size_t)m0 * Hn;
    const short* Bw = wb + (size_t)tensor * 65536 + (size_t)ncol0 * Hn;
    const float* bias = (tensor == 0) ? bq : (tensor == 1) ? bk : (tensor == 2) ? bv : btq;

    Acc acc;
#pragma unroll
    for (int i = 0; i < 4; ++i) acc.t[i] = (f32x4){0.f, 0.f, 0.f, 0.f};
    gemm_tile_64_cv<true, false>(A, Bw, As, Bs, acc);

    const int lane = threadIdx.x & 63, w = threadIdx.x >> 6;
    const int quad = lane >> 4, lm = lane & 15;

    if (tensor == 2) {
        // transposed V write: vt[((b*NH + h)*DH + d)*Ln + l]
#pragma unroll
        for (int kt = 0; kt < 4; ++kt) {
            int n = ncol0 + kt * 16 + lm;
            float bs = bv[n];
            int h = n >> 6, d = n & 63;
#pragma unroll
            for (int r = 0; r < 4; ++r) {
                int row = m0 + w * 16 + quad * 4 + r;
                int bb = row >> 9, l = row & 511;
                vt[((size_t)(bb * NHn + h) * DHn + d) * Ln + l] = f2b(acc.t[kt][r] + bs);
            }
        }
    } else {
        short* out = (tensor == 0) ? qb : (tensor == 1) ? kb : tqb;
#pragma unroll
        for (int kt = 0; kt < 4; ++kt) {
            int n = ncol0 + kt * 16 + lm;
            float bs = bias[n];
#pragma unroll
            for (int r = 0; r < 4; ++r) {
                int row = m0 + w * 16 + quad * 4 + r;
                out[(size_t)row * Hn + n] = f2b(acc.t[kt][r] + bs);
            }
        }
    }
}

// ---------------- time-decay gate (bf16, fragment-tiled out, incl /sqrt(DH)) ----------------
// A = tqb bf16; B staged directly from x fp32. Time matrices read as r5: coalesced
// scalar fp32 (16 adjacent lanes per 64B line).
__global__ __launch_bounds__(256) void gate_kernel(
    const short* __restrict__ tqb, const float* __restrict__ x,
    const float* __restrict__ tseq,
    const float* __restrict__ tw1, const float* __restrict__ tb1,
    const float* __restrict__ tow1, const float* __restrict__ tow2,
    const float* __restrict__ tob,
    short* __restrict__ gateb)
{
    __shared__ short As[64 * 72];
    __shared__ short Bs[64 * 72];
    const int b = blockIdx.z;
    const int m0 = blockIdx.y * 64, n0 = blockIdx.x * 64;
    const short* A = tqb + ((size_t)b * Ln + m0) * Hn;
    const float* Bw = x + ((size_t)b * Ln + n0) * Hn;

    Acc acc;
#pragma unroll
    for (int i = 0; i < 4; ++i) acc.t[i] = (f32x4){0.f, 0.f, 0.f, 0.f};
    gemm_tile_64_cv<false, true>(A, Bw, As, Bs, acc);

    const int tid = threadIdx.x;
    const int lane = tid & 63, w = tid >> 6;
    const int quad = lane >> 4, lm = lane & 15;
    const float* ts = tseq + (size_t)b * Ln;
    float ti[4];
#pragma unroll
    for (int r = 0; r < 4; ++r) ti[r] = ts[m0 + w * 16 + quad * 4 + r];

    bf16x8 g01, g23;
#pragma unroll
    for (int kt = 0; kt < 4; ++kt) {
        int j = n0 + kt * 16 + lm;
        float tj = ts[j];
#pragma unroll
        for (int r = 0; r < 4; ++r) {
            int i = m0 + w * 16 + quad * 4 + r;
            size_t ij = (size_t)i * Ln + j;
            float lg = __logf(1.f + fabsf(ti[r] - tj));
            float dec = fast_tanh(lg * tw1[ij] + tb1[ij]);
            float tqk = fast_tanh(acc.t[kt][r]);
            float dg = tow1[ij] * dec + tow2[ij] * tqk + tob[ij];
            float gv = 0.125f * fast_sigmoid(dg);
            if (kt < 2) g01[kt * 4 + r] = f2b(gv);
            else        g23[(kt - 2) * 4 + r] = f2b(gv);
        }
    }
    size_t base = ((((size_t)b * 8 + blockIdx.y) * 8 + blockIdx.x) * 256 + tid) * 16;
    *(bf16x8*)(gateb + base) = g01;
    *(bf16x8*)(gateb + base + 8) = g23;
}

// ---------------- flash attention, bf16 MFMA (r5 exact: vec gate loads, fp32 mask) ----------------
// grid (qt 8-wide, h, b): same-(b,qt) head blocks sit 8 apart -> same XCD -> L2 dedup.
__global__ __launch_bounds__(256) void flash_mfma(
    const short* __restrict__ qb, const short* __restrict__ kb,
    const short* __restrict__ vt, const short* __restrict__ gateb,
    const float* __restrict__ mask, short* __restrict__ ctxb)
{
    __shared__ short Ks[64 * 72];
    __shared__ short Vt[64 * 72];
    __shared__ short Ps[4 * 16 * 72];
    const int mb = blockIdx.x;          // q-tile index
    const int q0 = mb * 64;
    const int h = blockIdx.y, b = blockIdx.z;
    const int tid = threadIdx.x;
    const int w = tid >> 6, lane = tid & 63;
    const int quad = lane >> 4, lm = lane & 15;
    const int srow = tid >> 3, slot = tid & 7;

    bf16x8 qf0, qf1;
    {
        const short* qrow = qb + ((size_t)(b * Ln + q0 + w * 16 + lm)) * Hn + h * DHn;
        qf0 = *(const bf16x8*)(qrow + quad * 8);
        qf1 = *(const bf16x8*)(qrow + 32 + quad * 8);
    }

    f32x4 o[4];
#pragma unroll
    for (int i = 0; i < 4; ++i) o[i] = (f32x4){0.f, 0.f, 0.f, 0.f};
    float m_run[4] = {-INFINITY, -INFINITY, -INFINITY, -INFINITY};
    float l_run[4] = {0.f, 0.f, 0.f, 0.f};
    const float* mk_base = mask + (size_t)b * Ln * Ln;
    const int qrow0 = q0 + w * 16 + quad * 4;
    const short* kbase = kb + ((size_t)(b * Ln)) * Hn + h * DHn;
    const short* vbase = vt + (size_t)(b * NHn + h) * DHn * Ln;
    const short* gtile0 = gateb + (((size_t)b * 8 + mb) * 8 * 256 + tid) * 16;

    for (int k0 = 0; k0 < Ln; k0 += 64) {
        __syncthreads();
        // stage K [key][d] and V^T [d][key], both vectorized, stride-72 rows
#pragma unroll
        for (int iss = 0; iss < 2; ++iss) {
            int r = srow + iss * 32;
            bf16x8 kv = *(const bf16x8*)(kbase + (size_t)(k0 + r) * Hn + slot * 8);
            bf16x8 vv = *(const bf16x8*)(vbase + (size_t)r * Ln + k0 + slot * 8);
            *(bf16x8*)(Ks + r * 72 + slot * 8) = kv;
            *(bf16x8*)(Vt + r * 72 + slot * 8) = vv;
        }
        __syncthreads();

        // early-issue gate (2 vector loads) + mask (16 scalar): hide under MFMAs
        const short* gt = gtile0 + (size_t)(k0 >> 6) * 256 * 16;
        bf16x8 g01 = *(const bf16x8*)(gt);
        bf16x8 g23 = *(const bf16x8*)(gt + 8);
        float mvv[4][4];
#pragma unroll
        for (int kt = 0; kt < 4; ++kt) {
            int col = k0 + kt * 16 + lm;
#pragma unroll
            for (int r = 0; r < 4; ++r)
                mvv[kt][r] = mk_base[(size_t)(qrow0 + r) * Ln + col];
        }

        // S = Q K^T
        f32x4 s[4];
#pragma unroll
        for (int kt = 0; kt < 4; ++kt) {
            s[kt] = (f32x4){0.f, 0.f, 0.f, 0.f};
            bf16x8 b0 = *(const bf16x8*)(Ks + (kt * 16 + lm) * 72 + quad * 8);
            s[kt] = __builtin_amdgcn_mfma_f32_16x16x32_bf16(qf0, b0, s[kt], 0, 0, 0);
            bf16x8 b1 = *(const bf16x8*)(Ks + (kt * 16 + lm) * 72 + 32 + quad * 8);
            s[kt] = __builtin_amdgcn_mfma_f32_16x16x32_bf16(qf1, b1, s[kt], 0, 0, 0);
        }

        // s = s*gate + mask, online softmax
        float mnew[4];
#pragma unroll
        for (int r = 0; r < 4; ++r) mnew[r] = m_run[r];
#pragma unroll
        for (int kt = 0; kt < 4; ++kt)
#pragma unroll
            for (int r = 0; r < 4; ++r) {
                float g = b2f(kt < 2 ? g01[(kt & 1) * 4 + r] : g23[(kt & 1) * 4 + r]);
                float sv = s[kt][r] * g + mvv[kt][r];
                s[kt][r] = sv;
                mnew[r] = fmaxf(mnew[r], sv);
            }
        float alpha[4], rsum[4];
#pragma unroll
        for (int r = 0; r < 4; ++r) {
#pragma unroll
            for (int off = 1; off < 16; off <<= 1)
                mnew[r] = fmaxf(mnew[r], __shfl_xor(mnew[r], off, 64));
            alpha[r] = __expf(m_run[r] - mnew[r]);
            m_run[r] = mnew[r];
            rsum[r] = 0.f;
        }
        float p[4][4];
#pragma unroll
        for (int kt = 0; kt < 4; ++kt)
#pragma unroll
            for (int r = 0; r < 4; ++r) {
                float pv = __expf(s[kt][r] - m_run[r]);
                p[kt][r] = pv;
                rsum[r] += pv;
            }
#pragma unroll
        for (int r = 0; r < 4; ++r) {
#pragma unroll
            for (int off = 1; off < 16; off <<= 1) rsum[r] += __shfl_xor(rsum[r], off, 64);
            l_run[r] = l_run[r] * alpha[r] + rsum[r];
#pragma unroll
            for (int ot = 0; ot < 4; ++ot) o[ot][r] *= alpha[r];
        }
        // P -> LDS (per-wave region, no barrier), then PV
        short* pw = Ps + w * 16 * 72;
#pragma unroll
        for (int kt = 0; kt < 4; ++kt)
#pragma unroll
            for (int r = 0; r < 4; ++r)
                pw[(quad * 4 + r) * 72 + kt * 16 + lm] = f2b(p[kt][r]);

#pragma unroll
        for (int ks = 0; ks < 2; ++ks) {
            bf16x8 pa = *(const bf16x8*)(pw + lm * 72 + ks * 32 + quad * 8);
#pragma unroll
            for (int ot = 0; ot < 4; ++ot) {
                bf16x8 vv = *(const bf16x8*)(Vt + (ot * 16 + lm) * 72 + ks * 32 + quad * 8);
                o[ot] = __builtin_amdgcn_mfma_f32_16x16x32_bf16(pa, vv, o[ot], 0, 0, 0);
            }
        }
    }

    float inv[4];
#pragma unroll
    for (int r = 0; r < 4; ++r) inv[r] = 1.0f / l_run[r];
#pragma unroll
    for (int ot = 0; ot < 4; ++ot) {
        int d = h * DHn + ot * 16 + lm;
#pragma unroll
        for (int r = 0; r < 4; ++r) {
            int row = b * Ln + qrow0 + r;
            ctxb[(size_t)row * Hn + d] = f2b(o[ot][r] * inv[r]);
        }
    }
}

// ---------------- fused output projection + residual + LayerNorm + pred head ----------------
// 1024 blocks x 16-row stripes (r5 structure): wave w owns cols 64w..64w+63; LN closes
// via a small cross-wave LDS reduction. Pred head fused (r9-verified): per-row activity
// test handles loc1/loc2 straddling a stripe; each wave atomicAdds its 64-col partial.
__global__ __launch_bounds__(256) void outproj_ln_kernel(
    const short* __restrict__ ctxb, const short* __restrict__ wdb,
    const float* __restrict__ bd, const float* __restrict__ x,
    const float* __restrict__ g, const float* __restrict__ beta,
    const int* __restrict__ lens, const float* __restrict__ Wt,
    float* __restrict__ out, float* __restrict__ pred)
{
    const int m0 = blockIdx.x * 16;
    const int tid = threadIdx.x;
    const int lane = tid & 63, w = tid >> 6;
    const int quad = lane >> 4, lm = lane & 15;

    // A fragments: rows m0+lm, K quarter per quad (all waves load same rows; L2 hit)
    const short* arow = ctxb + (size_t)(m0 + lm) * Hn;
    bf16x8 af[8];
#pragma unroll
    for (int k8 = 0; k8 < 8; ++k8)
        af[k8] = *(const bf16x8*)(arow + k8 * 32 + quad * 8);

    f32x4 acc[4];
#pragma unroll
    for (int i = 0; i < 4; ++i) acc[i] = (f32x4){0.f, 0.f, 0.f, 0.f};

#pragma unroll
    for (int k8 = 0; k8 < 8; ++k8)
#pragma unroll
        for (int kt = 0; kt < 4; ++kt) {
            bf16x8 bf = *(const bf16x8*)(wdb + (size_t)(w * 64 + kt * 16 + lm) * Hn + k8 * 32 + quad * 8);
            acc[kt] = __builtin_amdgcn_mfma_f32_16x16x32_bf16(af[k8], bf, acc[kt], 0, 0, 0);
        }

    // bias + residual + per-wave partial LN sums (this wave's 64 cols)
    float s1[4] = {0.f, 0.f, 0.f, 0.f}, s2[4] = {0.f, 0.f, 0.f, 0.f};
#pragma unroll
    for (int kt = 0; kt < 4; ++kt) {
        int col = w * 64 + kt * 16 + lm;
        float bdv = bd[col];
#pragma unroll
        for (int r = 0; r < 4; ++r) {
            int row = m0 + quad * 4 + r;
            float xv = x[(size_t)row * Hn + col];
            float hv = acc[kt][r] + bdv + xv;
            acc[kt][r] = hv;
            s1[r] += hv;
            s2[r] += hv * hv;
        }
    }
#pragma unroll
    for (int r = 0; r < 4; ++r)
#pragma unroll
        for (int off = 1; off < 16; off <<= 1) {
            s1[r] += __shfl_xor(s1[r], off, 64);
            s2[r] += __shfl_xor(s2[r], off, 64);
        }
    __shared__ float red1[4][16], red2[4][16];
    if (lm == 0) {
#pragma unroll
        for (int r = 0; r < 4; ++r) {
            red1[w][quad * 4 + r] = s1[r];
            red2[w][quad * 4 + r] = s2[r];
        }
    }
    __syncthreads();
    float mu[4], rstd[4];
#pragma unroll
    for (int r = 0; r < 4; ++r) {
        int row = quad * 4 + r;
        float S1 = red1[0][row] + red1[1][row] + red1[2][row] + red1[3][row];
        float S2 = red2[0][row] + red2[1][row] + red2[2][row] + red2[3][row];
        mu[r] = S1 * (1.f / 256.f);
        float var = S2 * (1.f / 256.f) - mu[r] * mu[r];
        rstd[r] = rsqrtf(var + 1e-12f);
    }

    // pred rows for this stripe's batch (stripe lies within one batch: 16 | 512)
    const int bb = m0 >> 9;
    const int len = lens[bb];
    const int loc1 = (bb << 9) + len - 1;     // emb1 row (Wt[0:256])
    const int loc2 = loc1 - 1;                // emb2 row (Wt[256:512])
    const bool own1 = (loc1 >= m0) && (loc1 < m0 + 16);
    const bool own2 = (loc2 >= m0) && (loc2 < m0 + 16);
    const bool active = own1 || own2;
    float pacc = 0.f;

#pragma unroll
    for (int kt = 0; kt < 4; ++kt) {
        int col = w * 64 + kt * 16 + lm;
        float gv = g[col], bb2 = beta[col];
#pragma unroll
        for (int r = 0; r < 4; ++r) {
            int row = m0 + quad * 4 + r;
            float val = (acc[kt][r] - mu[r]) * rstd[r] * gv + bb2;
            out[(size_t)row * Hn + col] = val;
            if (active) {
                if (row == loc1) pacc += val * Wt[col];
                else if (row == loc2) pacc += val * Wt[Hn + col];
            }
        }
    }
    if (active) {
#pragma unroll
        for (int off = 1; off < 64; off <<= 1) pacc += __shfl_xor(pacc, off, 64);
        if (lane == 0) atomicAdd(&pred[bb], pacc);
    }
}

extern "C" void kernel_launch(void* const* d_in, const int* in_sizes, int n_in,
                              void* d_out, int out_size, void* d_ws, size_t ws_size,
                              hipStream_t stream) {
    (void)in_sizes; (void)n_in; (void)out_size; (void)ws_size;
    const float* x    = (const float*)d_in[0];
    const float* tseq = (const float*)d_in[1];
    const float* mask = (const float*)d_in[2];
    const int*   lens = (const int*)d_in[3];
    const float* Wq = (const float*)d_in[4];  const float* bq = (const float*)d_in[5];
    const float* Wk = (const float*)d_in[6];  const float* bk = (const float*)d_in[7];
    const float* Wv = (const float*)d_in[8];  const float* bv = (const float*)d_in[9];
    const float* Wd = (const float*)d_in[10]; const float* bd = (const float*)d_in[11];
    const float* ln_g = (const float*)d_in[12]; const float* ln_b = (const float*)d_in[13];
    const float* Wtq = (const float*)d_in[14]; const float* btq = (const float*)d_in[15];
    const float* tw1 = (const float*)d_in[16]; const float* tb1 = (const float*)d_in[17];
    const float* tow1 = (const float*)d_in[18]; const float* tow2 = (const float*)d_in[19];
    const float* tob = (const float*)d_in[20];
    const float* Wt = (const float*)d_in[21]; const float* bt = (const float*)d_in[22];

    const size_t NLH = (size_t)Bn * Ln * Hn;   // 4194304
    short* ws = (short*)d_ws;
    short* wb    = ws;                         // 5*65536
    short* qb    = wb + 5 * 65536;
    short* kb    = qb + NLH;
    short* vt    = kb + NLH;                   // transposed V: [b][h][d][l]
    short* tqb   = vt + NLH;
    short* gateb = tqb + NLH;                  // B*L*L bf16 gate, fragment-tiled
    short* ctxb  = tqb;                        // alias: tqb dead after gate_kernel
    float* out   = (float*)d_out;
    float* pred  = out + NLH;

    dim3 blk(256);
    conv_kernel<<<dim3(320), blk, 0, stream>>>(Wq, Wk, Wv, Wtq, Wd, bt, wb, pred);
    proj_kernel<<<dim3(16, 256), blk, 0, stream>>>(x, wb, bq, bk, bv, btq, qb, kb, vt, tqb);
    gate_kernel<<<dim3(8, 8, Bn), blk, 0, stream>>>(tqb, x, tseq, tw1, tb1, tow1, tow2, tob, gateb);
    flash_mfma<<<dim3(8, NHn, Bn), blk, 0, stream>>>(qb, kb, vt, gateb, mask, ctxb);
    outproj_ln_kernel<<<dim3(1024), blk, 0, stream>>>(ctxb, wb + 4 * 65536, bd, x,
                                                      ln_g, ln_b, lens, Wt, out, pred);
}

// Round 11
// 234.242 us; speedup vs baseline: 1.0573x; 1.0573x over previous
//
#include <hip/hip_runtime.h>
#include <math.h>

#define Bn 32
#define Ln 512
#define Hn 256
#define NHn 4
#define DHn 64

typedef __attribute__((ext_vector_type(8))) short bf16x8;
typedef __attribute__((ext_vector_type(4))) float f32x4;
typedef unsigned int uint32;

__device__ __forceinline__ short f2b(float f) {
    union { float f; uint32 u; } v; v.f = f;
    uint32 r = (v.u + 0x7FFFu + ((v.u >> 16) & 1u)) >> 16;
    return (short)r;
}
__device__ __forceinline__ float b2f(short h) {
    union { uint32 u; float f; } v; v.u = ((uint32)(unsigned short)h) << 16;
    return v.f;
}
// fast tanh: (e^{2x}-1)/(e^{2x}+1) = 1 - 2/(e^{2x}+1); exact limits at +-inf
__device__ __forceinline__ float fast_tanh(float x) {
    float e = __expf(2.f * x);
    return 1.f - 2.f * __builtin_amdgcn_rcpf(e + 1.f);
}
__device__ __forceinline__ float fast_sigmoid(float x) {
    return __builtin_amdgcn_rcpf(1.f + __expf(-x));
}

// ---------------- fp32 -> bf16 conversion: x (B*L*H) and 5 weight mats ----------------
__global__ __launch_bounds__(256) void conv_kernel(
    const float* __restrict__ x,
    const float* __restrict__ Wq, const float* __restrict__ Wk,
    const float* __restrict__ Wv, const float* __restrict__ Wtq,
    const float* __restrict__ Wd,
    short* __restrict__ xb, short* __restrict__ wb)
{
    const size_t NLH = (size_t)Bn * Ln * Hn;
    size_t i4 = ((size_t)blockIdx.x * 256 + threadIdx.x) * 4;
    if (i4 < NLH) {
        float4 v = *(const float4*)(x + i4);
        short4 o; o.x = f2b(v.x); o.y = f2b(v.y); o.z = f2b(v.z); o.w = f2b(v.w);
        *(short4*)(xb + i4) = o;
    } else {
        size_t off = i4 - NLH;                 // < 5*65536
        int w = (int)(off >> 16);
        size_t wi = off & 65535;
        const float* src = (w == 0) ? Wq : (w == 1) ? Wk : (w == 2) ? Wv : (w == 3) ? Wtq : Wd;
        float4 v = *(const float4*)(src + wi);
        short4 o; o.x = f2b(v.x); o.y = f2b(v.y); o.z = f2b(v.z); o.w = f2b(v.w);
        *(short4*)(wb + off) = o;
    }
}

// ---------------- shared 64x64 bf16 MFMA NT-GEMM tile (K multiple of 64) ----------------
struct Acc { f32x4 t[4]; };

__device__ __forceinline__ void gemm_tile_64(
    const short* __restrict__ A,   // rows m0.., row stride K
    const short* __restrict__ Bm,  // rows n0.., row stride K
    int K, short* As, short* Bs, Acc& acc)
{
    const int tid = threadIdx.x;
    const int lane = tid & 63, w = tid >> 6;
    const int quad = lane >> 4, lm = lane & 15;
    const int srow = tid >> 3;   // 0..31
    const int slot = tid & 7;

    for (int k0 = 0; k0 < K; k0 += 64) {
        __syncthreads();
#pragma unroll
        for (int iss = 0; iss < 2; ++iss) {
            int r = srow + iss * 32;
            bf16x8 av = *(const bf16x8*)(A + (size_t)r * K + k0 + slot * 8);
            bf16x8 bv = *(const bf16x8*)(Bm + (size_t)r * K + k0 + slot * 8);
            *(bf16x8*)(As + r * 72 + slot * 8) = av;
            *(bf16x8*)(Bs + r * 72 + slot * 8) = bv;
        }
        __syncthreads();
#pragma unroll
        for (int ks = 0; ks < 2; ++ks) {
            bf16x8 a = *(const bf16x8*)(As + (w * 16 + lm) * 72 + ks * 32 + quad * 8);
#pragma unroll
            for (int kt = 0; kt < 4; ++kt) {
                bf16x8 b = *(const bf16x8*)(Bs + (kt * 16 + lm) * 72 + ks * 32 + quad * 8);
                acc.t[kt] = __builtin_amdgcn_mfma_f32_16x16x32_bf16(a, b, acc.t[kt], 0, 0, 0);
            }
        }
    }
}

// ---------------- fused QKV+TQ projection (V written transposed: vt[b][h][d][l]) ----------------
// XCD-chunked swizzle: each XCD owns a contiguous m-range with all 16 (tensor,col)
// variants, so the shared A-tile is fetched from HBM once per XCD instead of 8x.
__global__ __launch_bounds__(256) void proj_kernel(
    const short* __restrict__ xb, const short* __restrict__ wb,
    const float* __restrict__ bq, const float* __restrict__ bk,
    const float* __restrict__ bv, const float* __restrict__ btq,
    short* __restrict__ qb, short* __restrict__ kb,
    short* __restrict__ vt, short* __restrict__ tqb)
{
    __shared__ short As[64 * 72];
    __shared__ short Bs[64 * 72];
    const int bid = blockIdx.y * 16 + blockIdx.x;      // dispatch-linear id
    const int xcd = bid & 7, idx = bid >> 3;
    const int v = xcd * 512 + idx;                     // bijective: 4096 blocks
    const int tensor = (v & 15) >> 2;
    const int ncol0 = (v & 3) * 64;
    const int m0 = (v >> 4) * 64;
    const short* A = xb + (size_t)m0 * Hn;
    const short* Bw = wb + (size_t)tensor * 65536 + (size_t)ncol0 * Hn;
    const float* bias = (tensor == 0) ? bq : (tensor == 1) ? bk : (tensor == 2) ? bv : btq;

    Acc acc;
#pragma unroll
    for (int i = 0; i < 4; ++i) acc.t[i] = (f32x4){0.f, 0.f, 0.f, 0.f};
    gemm_tile_64(A, Bw, Hn, As, Bs, acc);

    const int lane = threadIdx.x & 63, w = threadIdx.x >> 6;
    const int quad = lane >> 4, lm = lane & 15;

    if (tensor == 2) {
        // transposed V write: vt[((b*NH + h)*DH + d)*Ln + l]
#pragma unroll
        for (int kt = 0; kt < 4; ++kt) {
            int n = ncol0 + kt * 16 + lm;
            float bs = bv[n];
            int h = n >> 6, d = n & 63;
#pragma unroll
            for (int r = 0; r < 4; ++r) {
                int row = m0 + w * 16 + quad * 4 + r;
                int bb = row >> 9, l = row & 511;
                vt[((size_t)(bb * NHn + h) * DHn + d) * Ln + l] = f2b(acc.t[kt][r] + bs);
            }
        }
    } else {
        short* out = (tensor == 0) ? qb : (tensor == 1) ? kb : tqb;
#pragma unroll
        for (int kt = 0; kt < 4; ++kt) {
            int n = ncol0 + kt * 16 + lm;
            float bs = bias[n];
#pragma unroll
            for (int r = 0; r < 4; ++r) {
                int row = m0 + w * 16 + quad * 4 + r;
                out[(size_t)row * Hn + n] = f2b(acc.t[kt][r] + bs);
            }
        }
    }
}

// ---------------- time-decay gate (bf16, fragment-tiled layout, incl /sqrt(DH)) ----------------
// Output layout [b][mb][nb][tid][16]: thread tid of flash block (q-tile mb) at
// k-tile nb reads its 16 gate values as two contiguous bf16x8 vectors.
__global__ __launch_bounds__(256) void gate_kernel(
    const short* __restrict__ tqb, const short* __restrict__ xb,
    const float* __restrict__ tseq,
    const float* __restrict__ tw1, const float* __restrict__ tb1,
    const float* __restrict__ tow1, const float* __restrict__ tow2,
    const float* __restrict__ tob,
    short* __restrict__ gateb)
{
    __shared__ short As[64 * 72];
    __shared__ short Bs[64 * 72];
    const int b = blockIdx.z;
    const int m0 = blockIdx.y * 64, n0 = blockIdx.x * 64;
    const short* A = tqb + ((size_t)b * Ln + m0) * Hn;
    const short* Bw = xb + ((size_t)b * Ln + n0) * Hn;

    Acc acc;
#pragma unroll
    for (int i = 0; i < 4; ++i) acc.t[i] = (f32x4){0.f, 0.f, 0.f, 0.f};
    gemm_tile_64(A, Bw, Hn, As, Bs, acc);

    const int tid = threadIdx.x;
    const int lane = tid & 63, w = tid >> 6;
    const int quad = lane >> 4, lm = lane & 15;
    const float* ts = tseq + (size_t)b * Ln;
    float ti[4];
#pragma unroll
    for (int r = 0; r < 4; ++r) ti[r] = ts[m0 + w * 16 + quad * 4 + r];

    bf16x8 g01, g23;
#pragma unroll
    for (int kt = 0; kt < 4; ++kt) {
        int j = n0 + kt * 16 + lm;
        float tj = ts[j];
#pragma unroll
        for (int r = 0; r < 4; ++r) {
            int i = m0 + w * 16 + quad * 4 + r;
            size_t ij = (size_t)i * Ln + j;
            float lg = __logf(1.f + fabsf(ti[r] - tj));
            float dec = fast_tanh(lg * tw1[ij] + tb1[ij]);
            float tqk = fast_tanh(acc.t[kt][r]);
            float dg = tow1[ij] * dec + tow2[ij] * tqk + tob[ij];
            float g = 0.125f * fast_sigmoid(dg);
            if (kt < 2) g01[kt * 4 + r] = f2b(g);
            else        g23[(kt - 2) * 4 + r] = f2b(g);
        }
    }
    size_t base = ((((size_t)b * 8 + blockIdx.y) * 8 + blockIdx.x) * 256 + tid) * 16;
    *(bf16x8*)(gateb + base) = g01;
    *(bf16x8*)(gateb + base + 8) = g23;
}

// ---------------- flash attention, bf16 MFMA (vec gate loads, fp32 scalar mask) ----------------
// grid (qt 8-wide, h, b): same-(b,qt) head blocks sit 8 apart -> same XCD -> L2 dedup.
__global__ __launch_bounds__(256) void flash_mfma(
    const short* __restrict__ qb, const short* __restrict__ kb,
    const short* __restrict__ vt, const short* __restrict__ gateb,
    const float* __restrict__ mask, short* __restrict__ ctxb)
{
    __shared__ short Ks[64 * 72];
    __shared__ short Vt[64 * 72];
    __shared__ short Ps[4 * 16 * 72];
    const int mb = blockIdx.x;          // q-tile index
    const int q0 = mb * 64;
    const int h = blockIdx.y, b = blockIdx.z;
    const int tid = threadIdx.x;
    const int w = tid >> 6, lane = tid & 63;
    const int quad = lane >> 4, lm = lane & 15;
    const int srow = tid >> 3, slot = tid & 7;

    bf16x8 qf0, qf1;
    {
        const short* qrow = qb + ((size_t)(b * Ln + q0 + w * 16 + lm)) * Hn + h * DHn;
        qf0 = *(const bf16x8*)(qrow + quad * 8);
        qf1 = *(const bf16x8*)(qrow + 32 + quad * 8);
    }

    f32x4 o[4];
#pragma unroll
    for (int i = 0; i < 4; ++i) o[i] = (f32x4){0.f, 0.f, 0.f, 0.f};
    float m_run[4] = {-INFINITY, -INFINITY, -INFINITY, -INFINITY};
    float l_run[4] = {0.f, 0.f, 0.f, 0.f};
    const float* mk_base = mask + (size_t)b * Ln * Ln;
    const int qrow0 = q0 + w * 16 + quad * 4;
    const short* kbase = kb + ((size_t)(b * Ln)) * Hn + h * DHn;
    const short* vbase = vt + (size_t)(b * NHn + h) * DHn * Ln;
    const short* gtile0 = gateb + (((size_t)b * 8 + mb) * 8 * 256 + tid) * 16;

    for (int k0 = 0; k0 < Ln; k0 += 64) {
        __syncthreads();
        // stage K [key][d] and V^T [d][key], both vectorized, stride-72 rows
#pragma unroll
        for (int iss = 0; iss < 2; ++iss) {
            int r = srow + iss * 32;
            bf16x8 kv = *(const bf16x8*)(kbase + (size_t)(k0 + r) * Hn + slot * 8);
            bf16x8 vv = *(const bf16x8*)(vbase + (size_t)r * Ln + k0 + slot * 8);
            *(bf16x8*)(Ks + r * 72 + slot * 8) = kv;
            *(bf16x8*)(Vt + r * 72 + slot * 8) = vv;
        }
        __syncthreads();

        // early-issue gate (2 vector loads) + mask (16 scalar): hide under MFMAs
        const short* gt = gtile0 + (size_t)(k0 >> 6) * 256 * 16;
        bf16x8 g01 = *(const bf16x8*)(gt);
        bf16x8 g23 = *(const bf16x8*)(gt + 8);
        float mvv[4][4];
#pragma unroll
        for (int kt = 0; kt < 4; ++kt) {
            int col = k0 + kt * 16 + lm;
#pragma unroll
            for (int r = 0; r < 4; ++r)
                mvv[kt][r] = mk_base[(size_t)(qrow0 + r) * Ln + col];
        }

        // S = Q K^T
        f32x4 s[4];
#pragma unroll
        for (int kt = 0; kt < 4; ++kt) {
            s[kt] = (f32x4){0.f, 0.f, 0.f, 0.f};
            bf16x8 b0 = *(const bf16x8*)(Ks + (kt * 16 + lm) * 72 + quad * 8);
            s[kt] = __builtin_amdgcn_mfma_f32_16x16x32_bf16(qf0, b0, s[kt], 0, 0, 0);
            bf16x8 b1 = *(const bf16x8*)(Ks + (kt * 16 + lm) * 72 + 32 + quad * 8);
            s[kt] = __builtin_amdgcn_mfma_f32_16x16x32_bf16(qf1, b1, s[kt], 0, 0, 0);
        }

        // s = s*gate + mask, online softmax
        float mnew[4];
#pragma unroll
        for (int r = 0; r < 4; ++r) mnew[r] = m_run[r];
#pragma unroll
        for (int kt = 0; kt < 4; ++kt)
#pragma unroll
            for (int r = 0; r < 4; ++r) {
                float g = b2f(kt < 2 ? g01[(kt & 1) * 4 + r] : g23[(kt & 1) * 4 + r]);
                float sv = s[kt][r] * g + mvv[kt][r];
                s[kt][r] = sv;
                mnew[r] = fmaxf(mnew[r], sv);
            }
        float alpha[4], rsum[4];
#pragma unroll
        for (int r = 0; r < 4; ++r) {
#pragma unroll
            for (int off = 1; off < 16; off <<= 1)
                mnew[r] = fmaxf(mnew[r], __shfl_xor(mnew[r], off, 64));
            alpha[r] = __expf(m_run[r] - mnew[r]);
            m_run[r] = mnew[r];
            rsum[r] = 0.f;
        }
        float p[4][4];
#pragma unroll
        for (int kt = 0; kt < 4; ++kt)
#pragma unroll
            for (int r = 0; r < 4; ++r) {
                float pv = __expf(s[kt][r] - m_run[r]);
                p[kt][r] = pv;
                rsum[r] += pv;
            }
#pragma unroll
        for (int r = 0; r < 4; ++r) {
#pragma unroll
            for (int off = 1; off < 16; off <<= 1) rsum[r] += __shfl_xor(rsum[r], off, 64);
            l_run[r] = l_run[r] * alpha[r] + rsum[r];
#pragma unroll
            for (int ot = 0; ot < 4; ++ot) o[ot][r] *= alpha[r];
        }
        // P -> LDS (per-wave region, no barrier), then PV
        short* pw = Ps + w * 16 * 72;
#pragma unroll
        for (int kt = 0; kt < 4; ++kt)
#pragma unroll
            for (int r = 0; r < 4; ++r)
                pw[(quad * 4 + r) * 72 + kt * 16 + lm] = f2b(p[kt][r]);

#pragma unroll
        for (int ks = 0; ks < 2; ++ks) {
            bf16x8 pa = *(const bf16x8*)(pw + lm * 72 + ks * 32 + quad * 8);
#pragma unroll
            for (int ot = 0; ot < 4; ++ot) {
                bf16x8 vv = *(const bf16x8*)(Vt + (ot * 16 + lm) * 72 + ks * 32 + quad * 8);
                o[ot] = __builtin_amdgcn_mfma_f32_16x16x32_bf16(pa, vv, o[ot], 0, 0, 0);
            }
        }
    }

    float inv[4];
#pragma unroll
    for (int r = 0; r < 4; ++r) inv[r] = 1.0f / l_run[r];
#pragma unroll
    for (int ot = 0; ot < 4; ++ot) {
        int d = h * DHn + ot * 16 + lm;
#pragma unroll
        for (int r = 0; r < 4; ++r) {
            int row = b * Ln + qrow0 + r;
            ctxb[(size_t)row * Hn + d] = f2b(o[ot][r] * inv[r]);
        }
    }
}

// ---------------- fused output projection + residual + LayerNorm (fp32 out) ----------------
// 1024 blocks x 16-row stripes (4 blocks/CU): wave w owns cols 64w..64w+63; LN closes
// via a small cross-wave LDS reduction. No global-mem staging; Wd is L2-resident.
__global__ __launch_bounds__(256) void outproj_ln_kernel(
    const short* __restrict__ ctxb, const short* __restrict__ wdb,
    const float* __restrict__ bd, const float* __restrict__ x,
    const float* __restrict__ g, const float* __restrict__ beta,
    float* __restrict__ out)
{
    const int m0 = blockIdx.x * 16;
    const int tid = threadIdx.x;
    const int lane = tid & 63, w = tid >> 6;
    const int quad = lane >> 4, lm = lane & 15;

    // A fragments: rows m0+lm, K quarter per quad (all waves load same rows; L2 hit)
    const short* arow = ctxb + (size_t)(m0 + lm) * Hn;
    bf16x8 af[8];
#pragma unroll
    for (int k8 = 0; k8 < 8; ++k8)
        af[k8] = *(const bf16x8*)(arow + k8 * 32 + quad * 8);

    f32x4 acc[4];
#pragma unroll
    for (int i = 0; i < 4; ++i) acc[i] = (f32x4){0.f, 0.f, 0.f, 0.f};

#pragma unroll
    for (int k8 = 0; k8 < 8; ++k8)
#pragma unroll
        for (int kt = 0; kt < 4; ++kt) {
            bf16x8 bf = *(const bf16x8*)(wdb + (size_t)(w * 64 + kt * 16 + lm) * Hn + k8 * 32 + quad * 8);
            acc[kt] = __builtin_amdgcn_mfma_f32_16x16x32_bf16(af[k8], bf, acc[kt], 0, 0, 0);
        }

    // bias + residual + per-wave partial LN sums (this wave's 64 cols)
    float s1[4] = {0.f, 0.f, 0.f, 0.f}, s2[4] = {0.f, 0.f, 0.f, 0.f};
#pragma unroll
    for (int kt = 0; kt < 4; ++kt) {
        int col = w * 64 + kt * 16 + lm;
        float bdv = bd[col];
#pragma unroll
        for (int r = 0; r < 4; ++r) {
            int row = m0 + quad * 4 + r;
            float xv = x[(size_t)row * Hn + col];
            float hv = acc[kt][r] + bdv + xv;
            acc[kt][r] = hv;
            s1[r] += hv;
            s2[r] += hv * hv;
        }
    }
#pragma unroll
    for (int r = 0; r < 4; ++r)
#pragma unroll
        for (int off = 1; off < 16; off <<= 1) {
            s1[r] += __shfl_xor(s1[r], off, 64);
            s2[r] += __shfl_xor(s2[r], off, 64);
        }
    __shared__ float red1[4][16], red2[4][16];
    if (lm == 0) {
#pragma unroll
        for (int r = 0; r < 4; ++r) {
            red1[w][quad * 4 + r] = s1[r];
            red2[w][quad * 4 + r] = s2[r];
        }
    }
    __syncthreads();
    float mu[4], rstd[4];
#pragma unroll
    for (int r = 0; r < 4; ++r) {
        int row = quad * 4 + r;
        float S1 = red1[0][row] + red1[1][row] + red1[2][row] + red1[3][row];
        float S2 = red2[0][row] + red2[1][row] + red2[2][row] + red2[3][row];
        mu[r] = S1 * (1.f / 256.f);
        float var = S2 * (1.f / 256.f) - mu[r] * mu[r];
        rstd[r] = rsqrtf(var + 1e-12f);
    }
#pragma unroll
    for (int kt = 0; kt < 4; ++kt) {
        int col = w * 64 + kt * 16 + lm;
        float gv = g[col], bb = beta[col];
#pragma unroll
        for (int r = 0; r < 4; ++r)
            out[(size_t)(m0 + quad * 4 + r) * Hn + col] =
                (acc[kt][r] - mu[r]) * rstd[r] * gv + bb;
    }
}

// ---------------- prediction head ----------------
__global__ __launch_bounds__(256) void pred_kernel(const float* __restrict__ hs,
                                                   const int* __restrict__ lens,
                                                   const float* __restrict__ Wt,
                                                   const float* __restrict__ bt,
                                                   float* __restrict__ pred)
{
    const int b = blockIdx.x, t = threadIdx.x;
    int len = lens[b];
    float e1 = hs[((size_t)b * Ln + (len - 1)) * Hn + t];
    float e2 = hs[((size_t)b * Ln + (len - 2)) * Hn + t];
    float v = e1 * Wt[t] + e2 * Wt[Hn + t];
#pragma unroll
    for (int off = 32; off > 0; off >>= 1) v += __shfl_xor(v, off, 64);
    __shared__ float ps[4];
    if ((t & 63) == 0) ps[t >> 6] = v;
    __syncthreads();
    if (t == 0) pred[b] = ps[0] + ps[1] + ps[2] + ps[3] + bt[0];
}

extern "C" void kernel_launch(void* const* d_in, const int* in_sizes, int n_in,
                              void* d_out, int out_size, void* d_ws, size_t ws_size,
                              hipStream_t stream) {
    (void)in_sizes; (void)n_in; (void)out_size; (void)ws_size;
    const float* x    = (const float*)d_in[0];
    const float* tseq = (const float*)d_in[1];
    const float* mask = (const float*)d_in[2];
    const int*   lens = (const int*)d_in[3];
    const float* Wq = (const float*)d_in[4];  const float* bq = (const float*)d_in[5];
    const float* Wk = (const float*)d_in[6];  const float* bk = (const float*)d_in[7];
    const float* Wv = (const float*)d_in[8];  const float* bv = (const float*)d_in[9];
    const float* Wd = (const float*)d_in[10]; const float* bd = (const float*)d_in[11];
    const float* ln_g = (const float*)d_in[12]; const float* ln_b = (const float*)d_in[13];
    const float* Wtq = (const float*)d_in[14]; const float* btq = (const float*)d_in[15];
    const float* tw1 = (const float*)d_in[16]; const float* tb1 = (const float*)d_in[17];
    const float* tow1 = (const float*)d_in[18]; const float* tow2 = (const float*)d_in[19];
    const float* tob = (const float*)d_in[20];
    const float* Wt = (const float*)d_in[21]; const float* bt = (const float*)d_in[22];

    const size_t NLH = (size_t)Bn * Ln * Hn;   // 4194304
    short* ws = (short*)d_ws;
    short* xb    = ws;
    short* wb    = xb + NLH;                   // 5*65536
    short* qb    = wb + 5 * 65536;
    short* kb    = qb + NLH;
    short* vt    = kb + NLH;                   // transposed V: [b][h][d][l]
    short* tqb   = vt + NLH;
    short* gateb = tqb + NLH;                  // B*L*L bf16 gate, fragment-tiled
    short* ctxb  = tqb;                        // alias: tqb dead after gate_kernel
    float* out   = (float*)d_out;

    dim3 blk(256);
    conv_kernel<<<dim3(4416), blk, 0, stream>>>(x, Wq, Wk, Wv, Wtq, Wd, xb, wb);
    proj_kernel<<<dim3(16, 256), blk, 0, stream>>>(xb, wb, bq, bk, bv, btq, qb, kb, vt, tqb);
    gate_kernel<<<dim3(8, 8, Bn), blk, 0, stream>>>(tqb, xb, tseq, tw1, tb1, tow1, tow2, tob, gateb);
    flash_mfma<<<dim3(8, NHn, Bn), blk, 0, stream>>>(qb, kb, vt, gateb, mask, ctxb);
    outproj_ln_kernel<<<dim3(1024), blk, 0, stream>>>(ctxb, wb + 4 * 65536, bd, x, ln_g, ln_b, out);
    pred_kernel<<<dim3(Bn), blk, 0, stream>>>(out, lens, Wt, bt, out + NLH);
}

// Round 12
// 231.782 us; speedup vs baseline: 1.0686x; 1.0106x over previous
//
#include <hip/hip_runtime.h>
#include <math.h>

#define Bn 32
#define Ln 512
#define Hn 256
#define NHn 4
#define DHn 64

typedef __attribute__((ext_vector_type(8))) short bf16x8;
typedef __attribute__((ext_vector_type(4))) float f32x4;
typedef unsigned int uint32;

__device__ __forceinline__ short f2b(float f) {
    union { float f; uint32 u; } v; v.f = f;
    uint32 r = (v.u + 0x7FFFu + ((v.u >> 16) & 1u)) >> 16;
    return (short)r;
}
__device__ __forceinline__ float b2f(short h) {
    union { uint32 u; float f; } v; v.u = ((uint32)(unsigned short)h) << 16;
    return v.f;
}
// fast tanh: (e^{2x}-1)/(e^{2x}+1) = 1 - 2/(e^{2x}+1); exact limits at +-inf
__device__ __forceinline__ float fast_tanh(float x) {
    float e = __expf(2.f * x);
    return 1.f - 2.f * __builtin_amdgcn_rcpf(e + 1.f);
}
__device__ __forceinline__ float fast_sigmoid(float x) {
    return __builtin_amdgcn_rcpf(1.f + __expf(-x));
}

// ---------------- fp32 -> bf16 conversion: x (B*L*H) and 5 weight mats ----------------
__global__ __launch_bounds__(256) void conv_kernel(
    const float* __restrict__ x,
    const float* __restrict__ Wq, const float* __restrict__ Wk,
    const float* __restrict__ Wv, const float* __restrict__ Wtq,
    const float* __restrict__ Wd,
    short* __restrict__ xb, short* __restrict__ wb)
{
    const size_t NLH = (size_t)Bn * Ln * Hn;
    size_t i4 = ((size_t)blockIdx.x * 256 + threadIdx.x) * 4;
    if (i4 < NLH) {
        float4 v = *(const float4*)(x + i4);
        short4 o; o.x = f2b(v.x); o.y = f2b(v.y); o.z = f2b(v.z); o.w = f2b(v.w);
        *(short4*)(xb + i4) = o;
    } else {
        size_t off = i4 - NLH;                 // < 5*65536
        int w = (int)(off >> 16);
        size_t wi = off & 65535;
        const float* src = (w == 0) ? Wq : (w == 1) ? Wk : (w == 2) ? Wv : (w == 3) ? Wtq : Wd;
        float4 v = *(const float4*)(src + wi);
        short4 o; o.x = f2b(v.x); o.y = f2b(v.y); o.z = f2b(v.z); o.w = f2b(v.w);
        *(short4*)(wb + off) = o;
    }
}

// ---------------- shared 64x64 bf16 MFMA NT-GEMM tile (K multiple of 64) ----------------
struct Acc { f32x4 t[4]; };

__device__ __forceinline__ void gemm_tile_64(
    const short* __restrict__ A,   // rows m0.., row stride K
    const short* __restrict__ Bm,  // rows n0.., row stride K
    int K, short* As, short* Bs, Acc& acc)
{
    const int tid = threadIdx.x;
    const int lane = tid & 63, w = tid >> 6;
    const int quad = lane >> 4, lm = lane & 15;
    const int srow = tid >> 3;   // 0..31
    const int slot = tid & 7;

    for (int k0 = 0; k0 < K; k0 += 64) {
        __syncthreads();
#pragma unroll
        for (int iss = 0; iss < 2; ++iss) {
            int r = srow + iss * 32;
            bf16x8 av = *(const bf16x8*)(A + (size_t)r * K + k0 + slot * 8);
            bf16x8 bv = *(const bf16x8*)(Bm + (size_t)r * K + k0 + slot * 8);
            *(bf16x8*)(As + r * 72 + slot * 8) = av;
            *(bf16x8*)(Bs + r * 72 + slot * 8) = bv;
        }
        __syncthreads();
#pragma unroll
        for (int ks = 0; ks < 2; ++ks) {
            bf16x8 a = *(const bf16x8*)(As + (w * 16 + lm) * 72 + ks * 32 + quad * 8);
#pragma unroll
            for (int kt = 0; kt < 4; ++kt) {
                bf16x8 b = *(const bf16x8*)(Bs + (kt * 16 + lm) * 72 + ks * 32 + quad * 8);
                acc.t[kt] = __builtin_amdgcn_mfma_f32_16x16x32_bf16(a, b, acc.t[kt], 0, 0, 0);
            }
        }
    }
}

// ---------------- fused QKV+TQ projection, 128x128 tile (V transposed: vt[b][h][d][l]) ----
// Guide ladder m90->m93: 128^2 tile with the SAME simple 2-barrier schedule = 1.5x —
// 32 MFMAs per barrier-pair instead of 8, staging bytes per MFMA halved.
// Grid 1024 blocks: xcd = bid&7 owns contiguous m-tiles x all 8 n-tiles (A-tile L2-local).
// n-tile -> tensor is clean: each 256-col tensor = exactly two 128-col tiles.
__global__ __launch_bounds__(256) void proj_kernel(
    const short* __restrict__ xb, const short* __restrict__ wb,
    const float* __restrict__ bq, const float* __restrict__ bk,
    const float* __restrict__ bv, const float* __restrict__ btq,
    short* __restrict__ qb, short* __restrict__ kb,
    short* __restrict__ vt, short* __restrict__ tqb)
{
    __shared__ short As[128 * 72];
    __shared__ short Bs[128 * 72];
    const int bid = blockIdx.x;
    const int xcd = bid & 7, idx = bid >> 3;
    const int v = xcd * 128 + idx;            // bijective over 1024
    const int nt = v & 7, mt = v >> 3;        // nt: n-tile [0,8), mt: m-tile [0,128)
    const int tensor = nt >> 1;
    const int m0 = mt * 128;
    const short* A = xb + (size_t)m0 * Hn;
    const short* Bw = wb + (size_t)tensor * 65536 + (size_t)((nt & 1) * 128) * Hn;

    const int tid = threadIdx.x;
    const int lane = tid & 63, w = tid >> 6;
    const int wr = w >> 1, wc = w & 1;        // 2x2 wave grid, 64x64 each
    const int quad = lane >> 4, lm = lane & 15;
    const int srow = tid >> 3, slot = tid & 7;

    f32x4 acc[4][4];
#pragma unroll
    for (int m = 0; m < 4; ++m)
#pragma unroll
        for (int n = 0; n < 4; ++n) acc[m][n] = (f32x4){0.f, 0.f, 0.f, 0.f};

    for (int k0 = 0; k0 < Hn; k0 += 64) {
        __syncthreads();
#pragma unroll
        for (int iss = 0; iss < 4; ++iss) {
            int r = srow + iss * 32;
            bf16x8 av = *(const bf16x8*)(A + (size_t)r * Hn + k0 + slot * 8);
            bf16x8 bv2 = *(const bf16x8*)(Bw + (size_t)r * Hn + k0 + slot * 8);
            *(bf16x8*)(As + r * 72 + slot * 8) = av;
            *(bf16x8*)(Bs + r * 72 + slot * 8) = bv2;
        }
        __syncthreads();
#pragma unroll
        for (int ks = 0; ks < 2; ++ks) {
            bf16x8 a[4], b[4];
#pragma unroll
            for (int m = 0; m < 4; ++m)
                a[m] = *(const bf16x8*)(As + (wr * 64 + m * 16 + lm) * 72 + ks * 32 + quad * 8);
#pragma unroll
            for (int n = 0; n < 4; ++n)
                b[n] = *(const bf16x8*)(Bs + (wc * 64 + n * 16 + lm) * 72 + ks * 32 + quad * 8);
#pragma unroll
            for (int m = 0; m < 4; ++m)
#pragma unroll
                for (int n = 0; n < 4; ++n)
                    acc[m][n] = __builtin_amdgcn_mfma_f32_16x16x32_bf16(a[m], b[n], acc[m][n], 0, 0, 0);
        }
    }

    if (tensor == 2) {
        // transposed V write: vt[((b*NH + h)*DH + d)*Ln + l]
#pragma unroll
        for (int n = 0; n < 4; ++n) {
            int ncol = (nt & 1) * 128 + wc * 64 + n * 16 + lm;   // within tensor [0,256)
            float bs = bv[ncol];
            int h = ncol >> 6, d = ncol & 63;
#pragma unroll
            for (int m = 0; m < 4; ++m)
#pragma unroll
                for (int r = 0; r < 4; ++r) {
                    int row = m0 + wr * 64 + m * 16 + quad * 4 + r;
                    int bb = row >> 9, l = row & 511;
                    vt[((size_t)(bb * NHn + h) * DHn + d) * Ln + l] = f2b(acc[m][n][r] + bs);
                }
        }
    } else {
        short* out = (tensor == 0) ? qb : (tensor == 1) ? kb : tqb;
        const float* bias = (tensor == 0) ? bq : (tensor == 1) ? bk : btq;
#pragma unroll
        for (int n = 0; n < 4; ++n) {
            int ncol = (nt & 1) * 128 + wc * 64 + n * 16 + lm;
            float bs = bias[ncol];
#pragma unroll
            for (int m = 0; m < 4; ++m)
#pragma unroll
                for (int r = 0; r < 4; ++r) {
                    int row = m0 + wr * 64 + m * 16 + quad * 4 + r;
                    out[(size_t)row * Hn + ncol] = f2b(acc[m][n][r] + bs);
                }
        }
    }
}

// ---------------- time-decay gate (bf16, fragment-tiled layout, incl /sqrt(DH)) ----------------
// Output layout [b][mb][nb][tid][16]: thread tid of flash block (q-tile mb) at
// k-tile nb reads its 16 gate values as two contiguous bf16x8 vectors.
__global__ __launch_bounds__(256) void gate_kernel(
    const short* __restrict__ tqb, const short* __restrict__ xb,
    const float* __restrict__ tseq,
    const float* __restrict__ tw1, const float* __restrict__ tb1,
    const float* __restrict__ tow1, const float* __restrict__ tow2,
    const float* __restrict__ tob,
    short* __restrict__ gateb)
{
    __shared__ short As[64 * 72];
    __shared__ short Bs[64 * 72];
    const int b = blockIdx.z;
    const int m0 = blockIdx.y * 64, n0 = blockIdx.x * 64;
    const short* A = tqb + ((size_t)b * Ln + m0) * Hn;
    const short* Bw = xb + ((size_t)b * Ln + n0) * Hn;

    Acc acc;
#pragma unroll
    for (int i = 0; i < 4; ++i) acc.t[i] = (f32x4){0.f, 0.f, 0.f, 0.f};
    gemm_tile_64(A, Bw, Hn, As, Bs, acc);

    const int tid = threadIdx.x;
    const int lane = tid & 63, w = tid >> 6;
    const int quad = lane >> 4, lm = lane & 15;
    const float* ts = tseq + (size_t)b * Ln;
    float ti[4];
#pragma unroll
    for (int r = 0; r < 4; ++r) ti[r] = ts[m0 + w * 16 + quad * 4 + r];

    bf16x8 g01, g23;
#pragma unroll
    for (int kt = 0; kt < 4; ++kt) {
        int j = n0 + kt * 16 + lm;
        float tj = ts[j];
#pragma unroll
        for (int r = 0; r < 4; ++r) {
            int i = m0 + w * 16 + quad * 4 + r;
            size_t ij = (size_t)i * Ln + j;
            float lg = __logf(1.f + fabsf(ti[r] - tj));
            float dec = fast_tanh(lg * tw1[ij] + tb1[ij]);
            float tqk = fast_tanh(acc.t[kt][r]);
            float dg = tow1[ij] * dec + tow2[ij] * tqk + tob[ij];
            float g = 0.125f * fast_sigmoid(dg);
            if (kt < 2) g01[kt * 4 + r] = f2b(g);
            else        g23[(kt - 2) * 4 + r] = f2b(g);
        }
    }
    size_t base = ((((size_t)b * 8 + blockIdx.y) * 8 + blockIdx.x) * 256 + tid) * 16;
    *(bf16x8*)(gateb + base) = g01;
    *(bf16x8*)(gateb + base + 8) = g23;
}

// ---------------- flash attention, bf16 MFMA (vec gate loads, fp32 scalar mask) ----------------
// grid (qt 8-wide, h, b): same-(b,qt) head blocks sit 8 apart -> same XCD -> L2 dedup.
__global__ __launch_bounds__(256) void flash_mfma(
    const short* __restrict__ qb, const short* __restrict__ kb,
    const short* __restrict__ vt, const short* __restrict__ gateb,
    const float* __restrict__ mask, short* __restrict__ ctxb)
{
    __shared__ short Ks[64 * 72];
    __shared__ short Vt[64 * 72];
    __shared__ short Ps[4 * 16 * 72];
    const int mb = blockIdx.x;          // q-tile index
    const int q0 = mb * 64;
    const int h = blockIdx.y, b = blockIdx.z;
    const int tid = threadIdx.x;
    const int w = tid >> 6, lane = tid & 63;
    const int quad = lane >> 4, lm = lane & 15;
    const int srow = tid >> 3, slot = tid & 7;

    bf16x8 qf0, qf1;
    {
        const short* qrow = qb + ((size_t)(b * Ln + q0 + w * 16 + lm)) * Hn + h * DHn;
        qf0 = *(const bf16x8*)(qrow + quad * 8);
        qf1 = *(const bf16x8*)(qrow + 32 + quad * 8);
    }

    f32x4 o[4];
#pragma unroll
    for (int i = 0; i < 4; ++i) o[i] = (f32x4){0.f, 0.f, 0.f, 0.f};
    float m_run[4] = {-INFINITY, -INFINITY, -INFINITY, -INFINITY};
    float l_run[4] = {0.f, 0.f, 0.f, 0.f};
    const float* mk_base = mask + (size_t)b * Ln * Ln;
    const int qrow0 = q0 + w * 16 + quad * 4;
    const short* kbase = kb + ((size_t)(b * Ln)) * Hn + h * DHn;
    const short* vbase = vt + (size_t)(b * NHn + h) * DHn * Ln;
    const short* gtile0 = gateb + (((size_t)b * 8 + mb) * 8 * 256 + tid) * 16;

    for (int k0 = 0; k0 < Ln; k0 += 64) {
        __syncthreads();
        // stage K [key][d] and V^T [d][key], both vectorized, stride-72 rows
#pragma unroll
        for (int iss = 0; iss < 2; ++iss) {
            int r = srow + iss * 32;
            bf16x8 kv = *(const bf16x8*)(kbase + (size_t)(k0 + r) * Hn + slot * 8);
            bf16x8 vv = *(const bf16x8*)(vbase + (size_t)r * Ln + k0 + slot * 8);
            *(bf16x8*)(Ks + r * 72 + slot * 8) = kv;
            *(bf16x8*)(Vt + r * 72 + slot * 8) = vv;
        }
        __syncthreads();

        // early-issue gate (2 vector loads) + mask (16 scalar): hide under MFMAs
        const short* gt = gtile0 + (size_t)(k0 >> 6) * 256 * 16;
        bf16x8 g01 = *(const bf16x8*)(gt);
        bf16x8 g23 = *(const bf16x8*)(gt + 8);
        float mvv[4][4];
#pragma unroll
        for (int kt = 0; kt < 4; ++kt) {
            int col = k0 + kt * 16 + lm;
#pragma unroll
            for (int r = 0; r < 4; ++r)
                mvv[kt][r] = mk_base[(size_t)(qrow0 + r) * Ln + col];
        }

        // S = Q K^T
        f32x4 s[4];
#pragma unroll
        for (int kt = 0; kt < 4; ++kt) {
            s[kt] = (f32x4){0.f, 0.f, 0.f, 0.f};
            bf16x8 b0 = *(const bf16x8*)(Ks + (kt * 16 + lm) * 72 + quad * 8);
            s[kt] = __builtin_amdgcn_mfma_f32_16x16x32_bf16(qf0, b0, s[kt], 0, 0, 0);
            bf16x8 b1 = *(const bf16x8*)(Ks + (kt * 16 + lm) * 72 + 32 + quad * 8);
            s[kt] = __builtin_amdgcn_mfma_f32_16x16x32_bf16(qf1, b1, s[kt], 0, 0, 0);
        }

        // s = s*gate + mask, online softmax
        float mnew[4];
#pragma unroll
        for (int r = 0; r < 4; ++r) mnew[r] = m_run[r];
#pragma unroll
        for (int kt = 0; kt < 4; ++kt)
#pragma unroll
            for (int r = 0; r < 4; ++r) {
                float g = b2f(kt < 2 ? g01[(kt & 1) * 4 + r] : g23[(kt & 1) * 4 + r]);
                float sv = s[kt][r] * g + mvv[kt][r];
                s[kt][r] = sv;
                mnew[r] = fmaxf(mnew[r], sv);
            }
        float alpha[4], rsum[4];
#pragma unroll
        for (int r = 0; r < 4; ++r) {
#pragma unroll
            for (int off = 1; off < 16; off <<= 1)
                mnew[r] = fmaxf(mnew[r], __shfl_xor(mnew[r], off, 64));
            alpha[r] = __expf(m_run[r] - mnew[r]);
            m_run[r] = mnew[r];
            rsum[r] = 0.f;
        }
        float p[4][4];
#pragma unroll
        for (int kt = 0; kt < 4; ++kt)
#pragma unroll
            for (int r = 0; r < 4; ++r) {
                float pv = __expf(s[kt][r] - m_run[r]);
                p[kt][r] = pv;
                rsum[r] += pv;
            }
#pragma unroll
        for (int r = 0; r < 4; ++r) {
#pragma unroll
            for (int off = 1; off < 16; off <<= 1) rsum[r] += __shfl_xor(rsum[r], off, 64);
            l_run[r] = l_run[r] * alpha[r] + rsum[r];
#pragma unroll
            for (int ot = 0; ot < 4; ++ot) o[ot][r] *= alpha[r];
        }
        // P -> LDS (per-wave region, no barrier), then PV
        short* pw = Ps + w * 16 * 72;
#pragma unroll
        for (int kt = 0; kt < 4; ++kt)
#pragma unroll
            for (int r = 0; r < 4; ++r)
                pw[(quad * 4 + r) * 72 + kt * 16 + lm] = f2b(p[kt][r]);

#pragma unroll
        for (int ks = 0; ks < 2; ++ks) {
            bf16x8 pa = *(const bf16x8*)(pw + lm * 72 + ks * 32 + quad * 8);
#pragma unroll
            for (int ot = 0; ot < 4; ++ot) {
                bf16x8 vv = *(const bf16x8*)(Vt + (ot * 16 + lm) * 72 + ks * 32 + quad * 8);
                o[ot] = __builtin_amdgcn_mfma_f32_16x16x32_bf16(pa, vv, o[ot], 0, 0, 0);
            }
        }
    }

    float inv[4];
#pragma unroll
    for (int r = 0; r < 4; ++r) inv[r] = 1.0f / l_run[r];
#pragma unroll
    for (int ot = 0; ot < 4; ++ot) {
        int d = h * DHn + ot * 16 + lm;
#pragma unroll
        for (int r = 0; r < 4; ++r) {
            int row = b * Ln + qrow0 + r;
            ctxb[(size_t)row * Hn + d] = f2b(o[ot][r] * inv[r]);
        }
    }
}

// ---------------- fused output projection + residual + LayerNorm (fp32 out) ----------------
// 1024 blocks x 16-row stripes (4 blocks/CU): wave w owns cols 64w..64w+63; LN closes
// via a small cross-wave LDS reduction. No global-mem staging; Wd is L2-resident.
__global__ __launch_bounds__(256) void outproj_ln_kernel(
    const short* __restrict__ ctxb, const short* __restrict__ wdb,
    const float* __restrict__ bd, const float* __restrict__ x,
    const float* __restrict__ g, const float* __restrict__ beta,
    float* __restrict__ out)
{
    const int m0 = blockIdx.x * 16;
    const int tid = threadIdx.x;
    const int lane = tid & 63, w = tid >> 6;
    const int quad = lane >> 4, lm = lane & 15;

    // A fragments: rows m0+lm, K quarter per quad (all waves load same rows; L2 hit)
    const short* arow = ctxb + (size_t)(m0 + lm) * Hn;
    bf16x8 af[8];
#pragma unroll
    for (int k8 = 0; k8 < 8; ++k8)
        af[k8] = *(const bf16x8*)(arow + k8 * 32 + quad * 8);

    f32x4 acc[4];
#pragma unroll
    for (int i = 0; i < 4; ++i) acc[i] = (f32x4){0.f, 0.f, 0.f, 0.f};

#pragma unroll
    for (int k8 = 0; k8 < 8; ++k8)
#pragma unroll
        for (int kt = 0; kt < 4; ++kt) {
            bf16x8 bf = *(const bf16x8*)(wdb + (size_t)(w * 64 + kt * 16 + lm) * Hn + k8 * 32 + quad * 8);
            acc[kt] = __builtin_amdgcn_mfma_f32_16x16x32_bf16(af[k8], bf, acc[kt], 0, 0, 0);
        }

    // bias + residual + per-wave partial LN sums (this wave's 64 cols)
    float s1[4] = {0.f, 0.f, 0.f, 0.f}, s2[4] = {0.f, 0.f, 0.f, 0.f};
#pragma unroll
    for (int kt = 0; kt < 4; ++kt) {
        int col = w * 64 + kt * 16 + lm;
        float bdv = bd[col];
#pragma unroll
        for (int r = 0; r < 4; ++r) {
            int row = m0 + quad * 4 + r;
            float xv = x[(size_t)row * Hn + col];
            float hv = acc[kt][r] + bdv + xv;
            acc[kt][r] = hv;
            s1[r] += hv;
            s2[r] += hv * hv;
        }
    }
#pragma unroll
    for (int r = 0; r < 4; ++r)
#pragma unroll
        for (int off = 1; off < 16; off <<= 1) {
            s1[r] += __shfl_xor(s1[r], off, 64);
            s2[r] += __shfl_xor(s2[r], off, 64);
        }
    __shared__ float red1[4][16], red2[4][16];
    if (lm == 0) {
#pragma unroll
        for (int r = 0; r < 4; ++r) {
            red1[w][quad * 4 + r] = s1[r];
            red2[w][quad * 4 + r] = s2[r];
        }
    }
    __syncthreads();
    float mu[4], rstd[4];
#pragma unroll
    for (int r = 0; r < 4; ++r) {
        int row = quad * 4 + r;
        float S1 = red1[0][row] + red1[1][row] + red1[2][row] + red1[3][row];
        float S2 = red2[0][row] + red2[1][row] + red2[2][row] + red2[3][row];
        mu[r] = S1 * (1.f / 256.f);
        float var = S2 * (1.f / 256.f) - mu[r] * mu[r];
        rstd[r] = rsqrtf(var + 1e-12f);
    }
#pragma unroll
    for (int kt = 0; kt < 4; ++kt) {
        int col = w * 64 + kt * 16 + lm;
        float gv = g[col], bb = beta[col];
#pragma unroll
        for (int r = 0; r < 4; ++r)
            out[(size_t)(m0 + quad * 4 + r) * Hn + col] =
                (acc[kt][r] - mu[r]) * rstd[r] * gv + bb;
    }
}

// ---------------- prediction head ----------------
__global__ __launch_bounds__(256) void pred_kernel(const float* __restrict__ hs,
                                                   const int* __restrict__ lens,
                                                   const float* __restrict__ Wt,
                                                   const float* __restrict__ bt,
                                                   float* __restrict__ pred)
{
    const int b = blockIdx.x, t = threadIdx.x;
    int len = lens[b];
    float e1 = hs[((size_t)b * Ln + (len - 1)) * Hn + t];
    float e2 = hs[((size_t)b * Ln + (len - 2)) * Hn + t];
    float v = e1 * Wt[t] + e2 * Wt[Hn + t];
#pragma unroll
    for (int off = 32; off > 0; off >>= 1) v += __shfl_xor(v, off, 64);
    __shared__ float ps[4];
    if ((t & 63) == 0) ps[t >> 6] = v;
    __syncthreads();
    if (t == 0) pred[b] = ps[0] + ps[1] + ps[2] + ps[3] + bt[0];
}

extern "C" void kernel_launch(void* const* d_in, const int* in_sizes, int n_in,
                              void* d_out, int out_size, void* d_ws, size_t ws_size,
                              hipStream_t stream) {
    (void)in_sizes; (void)n_in; (void)out_size; (void)ws_size;
    const float* x    = (const float*)d_in[0];
    const float* tseq = (const float*)d_in[1];
    const float* mask = (const float*)d_in[2];
    const int*   lens = (const int*)d_in[3];
    const float* Wq = (const float*)d_in[4];  const float* bq = (const float*)d_in[5];
    const float* Wk = (const float*)d_in[6];  const float* bk = (const float*)d_in[7];
    const float* Wv = (const float*)d_in[8];  const float* bv = (const float*)d_in[9];
    const float* Wd = (const float*)d_in[10]; const float* bd = (const float*)d_in[11];
    const float* ln_g = (const float*)d_in[12]; const float* ln_b = (const float*)d_in[13];
    const float* Wtq = (const float*)d_in[14]; const float* btq = (const float*)d_in[15];
    const float* tw1 = (const float*)d_in[16]; const float* tb1 = (const float*)d_in[17];
    const float* tow1 = (const float*)d_in[18]; const float* tow2 = (const float*)d_in[19];
    const float* tob = (const float*)d_in[20];
    const float* Wt = (const float*)d_in[21]; const float* bt = (const float*)d_in[22];

    const size_t NLH = (size_t)Bn * Ln * Hn;   // 4194304
    short* ws = (short*)d_ws;
    short* xb    = ws;
    short* wb    = xb + NLH;                   // 5*65536
    short* qb    = wb + 5 * 65536;
    short* kb    = qb + NLH;
    short* vt    = kb + NLH;                   // transposed V: [b][h][d][l]
    short* tqb   = vt + NLH;
    short* gateb = tqb + NLH;                  // B*L*L bf16 gate, fragment-tiled
    short* ctxb  = tqb;                        // alias: tqb dead after gate_kernel
    float* out   = (float*)d_out;

    dim3 blk(256);
    conv_kernel<<<dim3(4416), blk, 0, stream>>>(x, Wq, Wk, Wv, Wtq, Wd, xb, wb);
    proj_kernel<<<dim3(1024), blk, 0, stream>>>(xb, wb, bq, bk, bv, btq, qb, kb, vt, tqb);
    gate_kernel<<<dim3(8, 8, Bn), blk, 0, stream>>>(tqb, xb, tseq, tw1, tb1, tow1, tow2, tob, gateb);
    flash_mfma<<<dim3(8, NHn, Bn), blk, 0, stream>>>(qb, kb, vt, gateb, mask, ctxb);
    outproj_ln_kernel<<<dim3(1024), blk, 0, stream>>>(ctxb, wb + 4 * 65536, bd, x, ln_g, ln_b, out);
    pred_kernel<<<dim3(Bn), blk, 0, stream>>>(out, lens, Wt, bt, out + NLH);
}